// Round 10
// baseline (290.378 us; speedup 1.0000x reference)
//
#include <hip/hip_runtime.h>

typedef _Float16 f16;
typedef f16 f16x4 __attribute__((ext_vector_type(4)));
typedef f16 f16x8 __attribute__((ext_vector_type(8)));
typedef float f32x4 __attribute__((ext_vector_type(4)));

#define RES 512
#define PTS 128     // kernel B: points per block (4 waves x 32 pts)
#define XS  136     // f16 stride, main K=128 region (+8 pad)
#define AS  16      // f16 stride, aug region: [nv(8) | bias=1 | zeros(7)]

// Two-kernel split (R9 post-mortem: gather latency and barriered MFMA at 8
// waves/CU starve each other; nothing saturated).
//  A: pure gather/sample at high occupancy -> nv f16 in d_ws [pt][32].
//  B: R9's MFMA MLP, nv loaded coalesced from ws. Sampling math bit-identical
//     to the R8-verified f32 variant-C chain (fma ascending-k).

// ---------------------------------------------------------------- kernel A
__global__ __launch_bounds__(256, 4)
void sample_kernel(const float* __restrict__ noise,
                   const float* __restrict__ coords,
                   const float* __restrict__ trans,
                   f16* __restrict__ nv_ws)
{
    __shared__ float T_sh[128];
    const int t = threadIdx.x;
    if (t < 128) T_sh[t] = trans[t];
    __syncthreads();

    const int gid = blockIdx.x * 256 + t;   // 0..524287
    const int p = gid >> 1, h = gid & 1;    // 2 threads per point, 16 feats each

    float nvr[16];
    {
        #pragma clang fp contract(off)
        const float cx = coords[p * 2 + 0];
        const float cy = coords[p * 2 + 1];
        #pragma unroll 4
        for (int k = 0; k < 16; ++k) {
            const int m = h * 16 + k;
            const float T00 = T_sh[m*4+0], T01 = T_sh[m*4+1];
            const float T10 = T_sh[m*4+2], T11 = T_sh[m*4+3];
            const float p0x = T00 * cx;                       // k=0: fl(cx*T00)
            const float p0y = T10 * cx;
            const float ncx = __builtin_fmaf(T01, cy, p0x);   // k=1: fused accumulate
            const float ncy = __builtin_fmaf(T11, cy, p0y);
            const float u = ncx - 0.5f;
            const float v = ncy - 0.5f;
            const float xf = floorf(u), yf = floorf(v);
            const float xw = u - xf, yw = v - yf;
            int ix = (xf >= 2147483648.0f || xf < -2147483648.0f) ? (int)(-2147483647 - 1) : (int)xf;
            int iy = (yf >= 2147483648.0f || yf < -2147483648.0f) ? (int)(-2147483647 - 1) : (int)yf;
            const int x0 = ix & (RES - 1);
            const int x1 = (int)(((unsigned)ix + 1u) & (unsigned)(RES - 1));
            const int y0 = iy & (RES - 1);
            const int y1 = (int)(((unsigned)iy + 1u) & (unsigned)(RES - 1));
            const float* pl = noise + m * (RES * RES);
            const float i00 = pl[y0 * RES + x0];
            const float i01 = pl[y0 * RES + x1];
            const float i10 = pl[y1 * RES + x0];
            const float i11 = pl[y1 * RES + x1];
            const float a0 = i00 + (i01 - i00) * xw;
            const float a1 = i10 + (i11 - i10) * xw;
            nvr[k] = a0 + (a1 - a0) * yw;
        }
    }
    f16x8 o0, o1;
    #pragma unroll
    for (int j = 0; j < 8; ++j) { o0[j] = (f16)nvr[j]; o1[j] = (f16)nvr[8 + j]; }
    *(f16x8*)&nv_ws[p * 32 + h * 16]     = o0;   // wave writes 2KB contiguous
    *(f16x8*)&nv_ws[p * 32 + h * 16 + 8] = o1;
}

// ---------------------------------------------------------------- kernel B
__global__ __launch_bounds__(256, 2)
void mlp_kernel(const f16* __restrict__ nv_ws,
                const float* __restrict__ input_vec,
                const float* __restrict__ lw,
                const float* __restrict__ lb,
                const float* __restrict__ lnw,
                const float* __restrict__ tw1,
                const float* __restrict__ tb1,
                const float* __restrict__ tw2,
                const float* __restrict__ tb2,
                float* __restrict__ out)
{
    __shared__ f16 Wm[128 * XS];        // 34816 B
    __shared__ f16 Waug[128 * AS];      //  4096 B
    __shared__ f16 xa[PTS * XS];        // 34816 B
    __shared__ f16 xaug[PTS * AS];      //  4096 B
    __shared__ __align__(16) float tw2_sh[128];

    const int t    = threadIdx.x;
    const int wave = t >> 6;
    const int lane = t & 63;
    const int q    = lane >> 4;
    const int l15  = lane & 15;
    const int pbase = blockIdx.x * PTS;
    const int pw    = wave * 32;        // wave-private point rows [pw, pw+32)
    const int p = t >> 1, h = t & 1;    // 2 threads per point (nv ownership)

    // ---------------- init ----------------
    if (t < 128) {
        tw2_sh[t] = tw2[t];
        xaug[t * AS + 8] = (f16)1.0f;          // bias lane
        #pragma unroll
        for (int c = 9; c < 16; ++c) { xaug[t * AS + c] = (f16)0.0f; Waug[t * AS + c] = (f16)0.0f; }
    }
    {   // xa rows = input_vec (f16); thread (p,h) fills its point's half-row
        #pragma unroll
        for (int j = 0; j < 8; ++j) {
            const float4 a = ((const float4*)input_vec)[h * 16 + j * 2];
            const float4 b = ((const float4*)input_vec)[h * 16 + j * 2 + 1];
            f16x8 hv;
            hv[0]=(f16)a.x; hv[1]=(f16)a.y; hv[2]=(f16)a.z; hv[3]=(f16)a.w;
            hv[4]=(f16)b.x; hv[5]=(f16)b.y; hv[6]=(f16)b.z; hv[7]=(f16)b.w;
            *(f16x8*)&xa[p * XS + h * 64 + j * 8] = hv;
        }
    }
    const float tb2_0 = tb2[0];

    // nv for this thread's point/half: 32B coalesced load from ws
    const f16x8 nva = *(const f16x8*)&nv_ws[(pbase + p) * 32 + h * 16];
    const f16x8 nvb = *(const f16x8*)&nv_ws[(pbase + p) * 32 + h * 16 + 8];
    if (h == 0) *(f16x8*)&xaug[p * AS] = nva;   // layer-0 feats 0..7 (same-wave reader)

    // ---------------- 5 MFMA layers ----------------
    f32x4 acc[2][8];
    #pragma unroll 1
    for (int L = 0; L < 5; ++L) {
        __syncthreads();   // all waves done reading previous Wm/Waug
        {   // stage W main (f32 -> f16, stride XS)
            const float* Wsrc = (L < 4) ? (lw + L * 16384) : tw1;
            #pragma unroll
            for (int i = 0; i < 16; ++i) {
                const int idx = t + i * 256;             // 0..4095 float4s
                const float4 w4 = ((const float4*)Wsrc)[idx];
                const int row = idx >> 5, c4 = (idx & 31) * 4;
                f16x4 hv;
                hv[0]=(f16)w4.x; hv[1]=(f16)w4.y; hv[2]=(f16)w4.z; hv[3]=(f16)w4.w;
                *(f16x4*)&Wm[row * XS + c4] = hv;
            }
            {   // Waug cols 0..7 = lnw slice (zeros for tw1)
                const int row = t >> 1, cc = (t & 1) * 4;
                f16x4 hv;
                if (L < 4) {
                    const float4 w4 = *(const float4*)(lnw + L * 1024 + row * 8 + cc);
                    hv[0]=(f16)w4.x; hv[1]=(f16)w4.y; hv[2]=(f16)w4.z; hv[3]=(f16)w4.w;
                } else {
                    hv[0]=(f16)0.f; hv[1]=(f16)0.f; hv[2]=(f16)0.f; hv[3]=(f16)0.f;
                }
                *(f16x4*)&Waug[row * AS + cc] = hv;
            }
            if (t < 128)   // Waug col 8 = bias
                Waug[t * AS + 8] = (f16)((L < 4) ? lb[L * 128 + t] : tb1[t]);
        }
        __syncthreads();

        {
            const f32x4 z4 = {0.f, 0.f, 0.f, 0.f};
            #pragma unroll
            for (int i = 0; i < 2; ++i)
                #pragma unroll
                for (int mt = 0; mt < 8; ++mt) acc[i][mt] = z4;
        }
        const int pr0 = (pw + l15) * XS, pr1 = (pw + 16 + l15) * XS;
        #pragma unroll
        for (int c = 0; c < 4; ++c) {   // main K=128
            const int kc = c * 32 + q * 8;
            const f16x8 xb0 = *(const f16x8*)&xa[pr0 + kc];
            const f16x8 xb1 = *(const f16x8*)&xa[pr1 + kc];
            #pragma unroll
            for (int mt = 0; mt < 8; ++mt) {
                const f16x8 aw = *(const f16x8*)&Wm[(mt * 16 + l15) * XS + kc];
                acc[0][mt] = __builtin_amdgcn_mfma_f32_16x16x32_f16(aw, xb0, acc[0][mt], 0, 0, 0);
                acc[1][mt] = __builtin_amdgcn_mfma_f32_16x16x32_f16(aw, xb1, acc[1][mt], 0, 0, 0);
            }
        }
        {   // aug chunk: quads 0-1 read 16 aug cols, quads 2-3 contribute zeros
            f16x8 xb0 = {}, xb1 = {};
            if (q < 2) {
                xb0 = *(const f16x8*)&xaug[(pw + l15) * AS + q * 8];
                xb1 = *(const f16x8*)&xaug[(pw + 16 + l15) * AS + q * 8];
            }
            #pragma unroll
            for (int mt = 0; mt < 8; ++mt) {
                f16x8 aw = {};
                if (q < 2) aw = *(const f16x8*)&Waug[(mt * 16 + l15) * AS + q * 8];
                acc[0][mt] = __builtin_amdgcn_mfma_f32_16x16x32_f16(aw, xb0, acc[0][mt], 0, 0, 0);
                acc[1][mt] = __builtin_amdgcn_mfma_f32_16x16x32_f16(aw, xb1, acc[1][mt], 0, 0, 0);
            }
        }

        if (L < 4) {
            // epilogue: leaky-relu + pack; wave-private xa rows -> no barrier
            #pragma unroll
            for (int i = 0; i < 2; ++i) {
                const int pr = (pw + i * 16 + l15) * XS;
                #pragma unroll
                for (int mt = 0; mt < 8; ++mt) {
                    f16x4 hv;
                    #pragma unroll
                    for (int r = 0; r < 4; ++r) {
                        float v = acc[i][mt][r];
                        v = fmaxf(v, 0.01f * v);
                        hv[r] = (f16)v;
                    }
                    *(f16x4*)&xa[pr + mt * 16 + q * 4] = hv;
                }
            }
            if (L < 3) {   // next layer's nv into xaug (owning thread; same-wave reader)
                const int Ln = L + 1;
                if ((Ln >> 1) == h)
                    *(f16x8*)&xaug[p * AS] = (Ln & 1) ? nvb : nva;
            }
        } else {
            // head: out = tw2 . lrelu(h) + tb2; butterfly over quads
            #pragma unroll
            for (int i = 0; i < 2; ++i) {
                float s = 0.f;
                #pragma unroll
                for (int mt = 0; mt < 8; ++mt) {
                    const f32x4 w4 = *(const f32x4*)&tw2_sh[mt * 16 + q * 4];
                    #pragma unroll
                    for (int r = 0; r < 4; ++r) {
                        float v = acc[i][mt][r];
                        v = fmaxf(v, 0.01f * v);
                        s += w4[r] * v;
                    }
                }
                s += __shfl_xor(s, 16);
                s += __shfl_xor(s, 32);
                if (q == 0) out[pbase + pw + i * 16 + l15] = s + tb2_0;
            }
        }
    }
}

extern "C" void kernel_launch(void* const* d_in, const int* in_sizes, int n_in,
                              void* d_out, int out_size, void* d_ws, size_t ws_size,
                              hipStream_t stream) {
    const float* noise  = (const float*)d_in[0];
    const float* coords = (const float*)d_in[1];
    const float* trans  = (const float*)d_in[2];
    const float* ivec   = (const float*)d_in[3];
    const float* lw     = (const float*)d_in[4];
    const float* lb     = (const float*)d_in[5];
    const float* lnw    = (const float*)d_in[6];
    const float* tw1    = (const float*)d_in[7];
    const float* tb1    = (const float*)d_in[8];
    const float* tw2    = (const float*)d_in[9];
    const float* tb2    = (const float*)d_in[10];
    float* o            = (float*)d_out;
    f16* nv_ws          = (f16*)d_ws;          // N*32 f16 = 16.8 MB

    const int N = in_sizes[1] / 2;             // coords is [N,2]
    sample_kernel<<<N * 2 / 256, 256, 0, stream>>>(noise, coords, trans, nv_ws);
    mlp_kernel<<<N / PTS, 256, 0, stream>>>(nv_ws, ivec, lw, lb, lnw,
                                            tw1, tb1, tw2, tb2, o);
}

// Round 11
// 253.149 us; speedup vs baseline: 1.1471x; 1.1471x over previous
//
#include <hip/hip_runtime.h>

typedef _Float16 f16;
typedef f16 f16x4 __attribute__((ext_vector_type(4)));
typedef f16 f16x8 __attribute__((ext_vector_type(8)));
typedef float f32x4 __attribute__((ext_vector_type(4)));

#define RES 512
#define PTS 128     // mlp: points per block (4 waves x 32 pts)
#define XS  136     // f16 stride, xa main K=128 region (+8 pad)
#define AS  16      // f16 stride, aug region: [nv(8) | bias=1 | zeros(7)]

// R10 post-mortem: sample (126us) was self-capped at 4 blocks/CU and L2-thrashed
// (32 x 1MB f32 planes vs 4MB XCD L2); mlp (~94us) paid 4-way LDS conflicts on
// aw reads + f32 weight staging. This round:
//  - pack_noise: f32->f16 planes (0.5MB -> L2-resident), guarded by ws_size.
//  - pack_w: weights+lnw+bias pre-converted to f16 in MFMA-FRAGMENT order:
//    frag(mt,c)[lane=q*16+l15] = W[mt*16+l15][c*32+q*8 ..+7] -> mlp staging is a
//    linear f16 copy and aw ds_read_b128 is lane-linear (conflict-free).
//  - sample at 8 blocks/CU.
// Sampling index math bit-identical to the R8-verified f32 variant-C chain.

// ---------------------------------------------------------------- pack kernels
__global__ __launch_bounds__(256)
void pack_noise_k(const float* __restrict__ n, f16* __restrict__ o) {
    const int i = (blockIdx.x * 256 + threadIdx.x) * 4;
    const float4 v = *(const float4*)(n + i);
    f16x4 h; h[0]=(f16)v.x; h[1]=(f16)v.y; h[2]=(f16)v.z; h[3]=(f16)v.w;
    *(f16x4*)(o + i) = h;
}

__global__ __launch_bounds__(256)
void pack_w_k(const float* __restrict__ lw,  const float* __restrict__ lnw,
              const float* __restrict__ lb,  const float* __restrict__ tw1,
              const float* __restrict__ tb1,
              f16* __restrict__ wf, f16* __restrict__ waugf) {
    const int g = blockIdx.x * 256 + threadIdx.x;
    if (g < 10240) {            // Wm fragments: 5 layers x 32 frags x 64 lanes
        const int L = g >> 11, r = g & 2047;
        const int lane = r & 63, frag = r >> 6;
        const int q = lane >> 4, l15 = lane & 15;
        const int mt = frag >> 2, c = frag & 3;
        const float* src = ((L < 4) ? (lw + L * 16384) : tw1)
                           + (mt * 16 + l15) * 128 + c * 32 + q * 8;
        f16x8 h;
        #pragma unroll
        for (int j = 0; j < 8; ++j) h[j] = (f16)src[j];
        *(f16x8*)(wf + (size_t)g * 8) = h;
    } else {                    // Waug fragments: 5 layers x 8 frags x 64 lanes
        const int ga = g - 10240;            // < 2560
        const int L = ga >> 9, r = ga & 511;
        const int lane = r & 63, mt = r >> 6;
        const int q = lane >> 4, l15 = lane & 15;
        const int row = mt * 16 + l15;
        f16x8 h = {};
        if (q == 0 && L < 4) {               // k=0..7: lnw slice
            const float* src = lnw + L * 1024 + row * 8;
            #pragma unroll
            for (int j = 0; j < 8; ++j) h[j] = (f16)src[j];
        }
        if (q == 1)                          // k=8: bias
            h[0] = (f16)((L < 4) ? lb[L * 128 + row] : tb1[row]);
        *(f16x8*)(waugf + (size_t)ga * 8) = h;
    }
}

// ---------------------------------------------------------------- sample kernel
template <typename TT>
__global__ __launch_bounds__(256, 8)
void sample_kernel(const TT* __restrict__ noise,
                   const float* __restrict__ coords,
                   const float* __restrict__ trans,
                   f16* __restrict__ nv_ws)
{
    __shared__ float T_sh[128];
    const int t = threadIdx.x;
    if (t < 128) T_sh[t] = trans[t];
    __syncthreads();

    const int gid = blockIdx.x * 256 + t;
    const int p = gid >> 1, h = gid & 1;    // 2 threads per point, 16 feats each

    float nvr[16];
    {
        #pragma clang fp contract(off)
        const float cx = coords[p * 2 + 0];
        const float cy = coords[p * 2 + 1];
        #pragma unroll 4
        for (int k = 0; k < 16; ++k) {
            const int m = h * 16 + k;
            const float T00 = T_sh[m*4+0], T01 = T_sh[m*4+1];
            const float T10 = T_sh[m*4+2], T11 = T_sh[m*4+3];
            const float p0x = T00 * cx;                       // k=0: fl(cx*T00)
            const float p0y = T10 * cx;
            const float ncx = __builtin_fmaf(T01, cy, p0x);   // k=1: fused accumulate
            const float ncy = __builtin_fmaf(T11, cy, p0y);
            const float u = ncx - 0.5f;
            const float v = ncy - 0.5f;
            const float xf = floorf(u), yf = floorf(v);
            const float xw = u - xf, yw = v - yf;
            int ix = (xf >= 2147483648.0f || xf < -2147483648.0f) ? (int)(-2147483647 - 1) : (int)xf;
            int iy = (yf >= 2147483648.0f || yf < -2147483648.0f) ? (int)(-2147483647 - 1) : (int)yf;
            const int x0 = ix & (RES - 1);
            const int x1 = (int)(((unsigned)ix + 1u) & (unsigned)(RES - 1));
            const int y0 = iy & (RES - 1);
            const int y1 = (int)(((unsigned)iy + 1u) & (unsigned)(RES - 1));
            const TT* pl = noise + m * (RES * RES);
            const float i00 = (float)pl[y0 * RES + x0];
            const float i01 = (float)pl[y0 * RES + x1];
            const float i10 = (float)pl[y1 * RES + x0];
            const float i11 = (float)pl[y1 * RES + x1];
            const float a0 = i00 + (i01 - i00) * xw;
            const float a1 = i10 + (i11 - i10) * xw;
            nvr[k] = a0 + (a1 - a0) * yw;
        }
    }
    f16x8 o0, o1;
    #pragma unroll
    for (int j = 0; j < 8; ++j) { o0[j] = (f16)nvr[j]; o1[j] = (f16)nvr[8 + j]; }
    *(f16x8*)&nv_ws[p * 32 + h * 16]     = o0;
    *(f16x8*)&nv_ws[p * 32 + h * 16 + 8] = o1;
}

// ---------------------------------------------------------------- mlp kernel
__global__ __launch_bounds__(256, 2)
void mlp_kernel(const f16* __restrict__ nv_ws,
                const f16* __restrict__ wf,
                const f16* __restrict__ waugf,
                const float* __restrict__ input_vec,
                const float* __restrict__ tw2,
                const float* __restrict__ tb2,
                float* __restrict__ out)
{
    __shared__ f16 Wm[16384];           // 32 frags x 512 f16 = 32768 B, lane-linear
    __shared__ f16 Waug[4096];          //  8 frags x 512 f16 =  8192 B
    __shared__ f16 xa[PTS * XS];        // 34816 B
    __shared__ f16 xaug[PTS * AS];      //  4096 B
    __shared__ __align__(16) float tw2_sh[128];

    const int t    = threadIdx.x;
    const int wave = t >> 6;
    const int lane = t & 63;
    const int q    = lane >> 4;
    const int l15  = lane & 15;
    const int pbase = blockIdx.x * PTS;
    const int pw    = wave * 32;        // wave-private point rows [pw, pw+32)
    const int p = t >> 1, h = t & 1;    // 2 threads per point (nv ownership)

    // ---------------- init ----------------
    if (t < 128) {
        tw2_sh[t] = tw2[t];
        xaug[t * AS + 8] = (f16)1.0f;          // bias lane
        #pragma unroll
        for (int c = 9; c < 16; ++c) xaug[t * AS + c] = (f16)0.0f;
    }
    {   // xa rows = input_vec (f16); thread (p,h) fills its point's half-row
        #pragma unroll
        for (int j = 0; j < 8; ++j) {
            const float4 a = ((const float4*)input_vec)[h * 16 + j * 2];
            const float4 b = ((const float4*)input_vec)[h * 16 + j * 2 + 1];
            f16x8 hv;
            hv[0]=(f16)a.x; hv[1]=(f16)a.y; hv[2]=(f16)a.z; hv[3]=(f16)a.w;
            hv[4]=(f16)b.x; hv[5]=(f16)b.y; hv[6]=(f16)b.z; hv[7]=(f16)b.w;
            *(f16x8*)&xa[p * XS + h * 64 + j * 8] = hv;
        }
    }
    const float tb2_0 = tb2[0];

    // nv for this thread's point/half: coalesced 32B load from ws
    const f16x8 nva = *(const f16x8*)&nv_ws[(pbase + p) * 32 + h * 16];
    const f16x8 nvb = *(const f16x8*)&nv_ws[(pbase + p) * 32 + h * 16 + 8];
    if (h == 0) *(f16x8*)&xaug[p * AS] = nva;   // layer-0 feats 0..7 (same-wave reader)

    // ---------------- 5 MFMA layers ----------------
    f32x4 acc[2][8];
    #pragma unroll 1
    for (int L = 0; L < 5; ++L) {
        __syncthreads();   // all waves done reading previous Wm/Waug
        {   // stage W fragments: straight f16 copy, lane-linear both sides
            const f16* wsrc = wf + L * 16384;
            #pragma unroll
            for (int i = 0; i < 8; ++i) {
                const int idx = t + i * 256;
                *(f16x8*)&Wm[idx * 8] = *(const f16x8*)&wsrc[idx * 8];
            }
            const f16* asrc = waugf + L * 4096;
            *(f16x8*)&Waug[t * 8]         = *(const f16x8*)&asrc[t * 8];
            *(f16x8*)&Waug[(t + 256) * 8] = *(const f16x8*)&asrc[(t + 256) * 8];
        }
        __syncthreads();

        {
            const f32x4 z4 = {0.f, 0.f, 0.f, 0.f};
            #pragma unroll
            for (int i = 0; i < 2; ++i)
                #pragma unroll
                for (int mt = 0; mt < 8; ++mt) acc[i][mt] = z4;
        }
        const int pr0 = (pw + l15) * XS, pr1 = (pw + 16 + l15) * XS;
        #pragma unroll
        for (int c = 0; c < 4; ++c) {   // main K=128
            const int kc = c * 32 + q * 8;
            const f16x8 xb0 = *(const f16x8*)&xa[pr0 + kc];
            const f16x8 xb1 = *(const f16x8*)&xa[pr1 + kc];
            #pragma unroll
            for (int mt = 0; mt < 8; ++mt) {
                const f16x8 aw = *(const f16x8*)&Wm[((mt * 4 + c) * 64 + lane) * 8]; // conflict-free
                acc[0][mt] = __builtin_amdgcn_mfma_f32_16x16x32_f16(aw, xb0, acc[0][mt], 0, 0, 0);
                acc[1][mt] = __builtin_amdgcn_mfma_f32_16x16x32_f16(aw, xb1, acc[1][mt], 0, 0, 0);
            }
        }
        {   // aug chunk: A-side fully stored (zeros for q>=2), B-side exec-masked
            f16x8 xb0 = {}, xb1 = {};
            if (q < 2) {
                xb0 = *(const f16x8*)&xaug[(pw + l15) * AS + q * 8];
                xb1 = *(const f16x8*)&xaug[(pw + 16 + l15) * AS + q * 8];
            }
            #pragma unroll
            for (int mt = 0; mt < 8; ++mt) {
                const f16x8 aw = *(const f16x8*)&Waug[(mt * 64 + lane) * 8];
                acc[0][mt] = __builtin_amdgcn_mfma_f32_16x16x32_f16(aw, xb0, acc[0][mt], 0, 0, 0);
                acc[1][mt] = __builtin_amdgcn_mfma_f32_16x16x32_f16(aw, xb1, acc[1][mt], 0, 0, 0);
            }
        }

        if (L < 4) {
            // epilogue: leaky-relu + pack; wave-private xa rows -> no barrier
            #pragma unroll
            for (int i = 0; i < 2; ++i) {
                const int pr = (pw + i * 16 + l15) * XS;
                #pragma unroll
                for (int mt = 0; mt < 8; ++mt) {
                    f16x4 hv;
                    #pragma unroll
                    for (int r = 0; r < 4; ++r) {
                        float v = acc[i][mt][r];
                        v = fmaxf(v, 0.01f * v);
                        hv[r] = (f16)v;
                    }
                    *(f16x4*)&xa[pr + mt * 16 + q * 4] = hv;
                }
            }
            if (L < 3) {   // next layer's nv into xaug (owning thread; same-wave reader)
                const int Ln = L + 1;
                if ((Ln >> 1) == h)
                    *(f16x8*)&xaug[p * AS] = (Ln & 1) ? nvb : nva;
            }
        } else {
            // head: out = tw2 . lrelu(h) + tb2; butterfly over quads
            #pragma unroll
            for (int i = 0; i < 2; ++i) {
                float s = 0.f;
                #pragma unroll
                for (int mt = 0; mt < 8; ++mt) {
                    const f32x4 w4 = *(const f32x4*)&tw2_sh[mt * 16 + q * 4];
                    #pragma unroll
                    for (int r = 0; r < 4; ++r) {
                        float v = acc[i][mt][r];
                        v = fmaxf(v, 0.01f * v);
                        s += w4[r] * v;
                    }
                }
                s += __shfl_xor(s, 16);
                s += __shfl_xor(s, 32);
                if (q == 0) out[pbase + pw + i * 16 + l15] = s + tb2_0;
            }
        }
    }
}

extern "C" void kernel_launch(void* const* d_in, const int* in_sizes, int n_in,
                              void* d_out, int out_size, void* d_ws, size_t ws_size,
                              hipStream_t stream) {
    const float* noise  = (const float*)d_in[0];
    const float* coords = (const float*)d_in[1];
    const float* trans  = (const float*)d_in[2];
    const float* ivec   = (const float*)d_in[3];
    const float* lw     = (const float*)d_in[4];
    const float* lb     = (const float*)d_in[5];
    const float* lnw    = (const float*)d_in[6];
    const float* tw1    = (const float*)d_in[7];
    const float* tb1    = (const float*)d_in[8];
    const float* tw2    = (const float*)d_in[9];
    const float* tb2    = (const float*)d_in[10];
    float* o            = (float*)d_out;

    const int N = in_sizes[1] / 2;                    // coords is [N,2]
    // ws layout: nv (16 MiB) | wf (160 KiB) | waug (40 KiB) | noise_f16 (16 MiB, optional)
    f16* nv    = (f16*)d_ws;
    const size_t NV = (size_t)N * 32 * sizeof(f16);
    f16* wfp   = (f16*)((char*)d_ws + NV);
    f16* waugp = wfp + 5 * 16384;
    f16* nzp   = waugp + 5 * 4096;
    const size_t need_full = NV + (5 * 16384 + 5 * 4096) * sizeof(f16)
                           + (size_t)32 * RES * RES * sizeof(f16);

    pack_w_k<<<50, 256, 0, stream>>>(lw, lnw, lb, tw1, tb1, wfp, waugp);
    if (ws_size >= need_full) {   // ws_size constant across calls -> graph-safe branch
        pack_noise_k<<<(32 * RES * RES) / 1024, 256, 0, stream>>>(noise, nzp);
        sample_kernel<f16><<<N * 2 / 256, 256, 0, stream>>>(nzp, coords, trans, nv);
    } else {
        sample_kernel<float><<<N * 2 / 256, 256, 0, stream>>>(noise, coords, trans, nv);
    }
    mlp_kernel<<<N / PTS, 256, 0, stream>>>(nv, wfp, waugp, ivec, tw2, tb2, o);
}